// Round 14
// baseline (292.259 us; speedup 1.0000x reference)
//
#include <hip/hip_runtime.h>

typedef __attribute__((ext_vector_type(8))) __bf16 bf16x8;
typedef __attribute__((ext_vector_type(4))) float f32x4;

__device__ __forceinline__ unsigned short bf16s(float f) {
    __bf16 b = (__bf16)f;
    unsigned short u;
    __builtin_memcpy(&u, &b, 2);
    return u;
}
__device__ __forceinline__ unsigned pk2(float a, float b) {
    __bf16 lo = (__bf16)a, hi = (__bf16)b;
    unsigned short ul, uh;
    __builtin_memcpy(&ul, &lo, 2);
    __builtin_memcpy(&uh, &hi, 2);
    return (unsigned)ul | ((unsigned)uh << 16);
}
#define AS1(p) ((const __attribute__((address_space(1))) void*)(p))
#define AS3(p) ((__attribute__((address_space(3))) void*)(p))

// ---------------- K0: one-shot fp32 -> bf16 conversion of X (q,k,v) and W ----------------
__global__ __launch_bounds__(256) void convert_kernel(
    const float* __restrict__ q, const float* __restrict__ k, const float* __restrict__ v,
    const float* __restrict__ Wq, const float* __restrict__ Wk,
    const float* __restrict__ Wv, const float* __restrict__ Wfc,
    unsigned short* __restrict__ xb, unsigned short* __restrict__ wb)
{
    size_t i = ((size_t)blockIdx.x * 256 + threadIdx.x) * 8;
    const float* src;
    unsigned short* dst;
    size_t off;
    if (i < 12582912ull) {
        int a = (int)(i >> 22);
        src = a == 0 ? q : a == 1 ? k : v;
        off = i & 4194303ull;
        dst = xb + i;
    } else {
        size_t wi = i - 12582912ull;
        int a = (int)(wi >> 20);
        src = a == 0 ? Wq : a == 1 ? Wk : a == 2 ? Wv : Wfc;
        off = wi & 1048575ull;
        dst = wb + wi;
    }
    float4 v0 = *(const float4*)(src + off);
    float4 v1 = *(const float4*)(src + off + 4);
    int4 o;
    o.x = (int)pk2(v0.x, v0.y);
    o.y = (int)pk2(v0.z, v0.w);
    o.z = (int)pk2(v1.x, v1.y);
    o.w = (int)pk2(v1.z, v1.w);
    *(int4*)dst = o;
}

// ---------------- K1: QKV projection GEMM (bf16 in, + q_flat + vh transposed) ----------------
// qh is written PRE-SCALED by 1/8 (exact in bf16); qflat unscaled.
__global__ __launch_bounds__(256, 3) void qkv_proj_kernel(
    const unsigned short* __restrict__ xb, const unsigned short* __restrict__ wb,
    const float* __restrict__ bq, const float* __restrict__ bk, const float* __restrict__ bv,
    unsigned short* __restrict__ qh, unsigned short* __restrict__ kh,
    unsigned short* __restrict__ vht, float* __restrict__ qflat)
{
    __shared__ unsigned short lds_a[128 * 64];
    __shared__ unsigned short lds_b[128 * 64];

    const int nb = blockIdx.x;
    const int mb = blockIdx.y;
    const int proj = nb >> 3;
    const int n0 = (nb & 7) * 128;
    const int m0 = mb * 128;

    const unsigned short* A = xb + (size_t)proj * 4194304;
    const unsigned short* B = wb + (size_t)proj * 1048576;
    const float* bias = proj == 0 ? bq : proj == 1 ? bk : bv;

    const int t = threadIdx.x, l = t & 63, w = t >> 6;
    const int wr = w >> 1, wc = w & 1;
    const int li = l & 15, g = l >> 4;
    const int sr = l >> 3;
    const int us_st = (l & 7) ^ sr;

    f32x4 acc[4][4];
    #pragma unroll
    for (int i = 0; i < 4; i++)
        #pragma unroll
        for (int j = 0; j < 4; j++) acc[i][j] = (f32x4){0.f, 0.f, 0.f, 0.f};

    for (int k0 = 0; k0 < 1024; k0 += 64) {
        __syncthreads();
        #pragma unroll
        for (int i = 0; i < 4; i++) {
            int r = i * 32 + w * 8 + sr;
            __builtin_amdgcn_global_load_lds(AS1(A + (size_t)(m0 + r) * 1024 + k0 + us_st * 8),
                                             AS3(lds_a + (i * 256 + w * 64) * 8), 16, 0, 0);
            __builtin_amdgcn_global_load_lds(AS1(B + (size_t)(n0 + r) * 1024 + k0 + us_st * 8),
                                             AS3(lds_b + (i * 256 + w * 64) * 8), 16, 0, 0);
        }
        __syncthreads();
        #pragma unroll
        for (int kk = 0; kk < 2; kk++) {
            bf16x8 af[4], bfr[4];
            int us = (kk * 4 + g) ^ (li & 7);
            #pragma unroll
            for (int mi = 0; mi < 4; mi++)
                af[mi] = *(bf16x8*)&lds_a[(wr * 64 + mi * 16 + li) * 64 + us * 8];
            #pragma unroll
            for (int ni = 0; ni < 4; ni++)
                bfr[ni] = *(bf16x8*)&lds_b[(wc * 64 + ni * 16 + li) * 64 + us * 8];
            #pragma unroll
            for (int mi = 0; mi < 4; mi++)
                #pragma unroll
                for (int ni = 0; ni < 4; ni++)
                    acc[mi][ni] = __builtin_amdgcn_mfma_f32_16x16x32_bf16(af[mi], bfr[ni], acc[mi][ni], 0, 0, 0);
        }
    }

    if (proj == 2) {
        #pragma unroll
        for (int mi = 0; mi < 4; mi++)
            #pragma unroll
            for (int ni = 0; ni < 4; ni++) {
                int c = n0 + wc * 64 + ni * 16 + li;
                float bl = bias[c];
                int hh = c >> 6, dd = c & 63;
                int row0 = m0 + wr * 64 + mi * 16 + g * 4;
                int bb = row0 >> 11, kk2 = row0 & 2047;
                unsigned lo = pk2(acc[mi][ni][0] + bl, acc[mi][ni][1] + bl);
                unsigned hi = pk2(acc[mi][ni][2] + bl, acc[mi][ni][3] + bl);
                int2 u; u.x = (int)lo; u.y = (int)hi;
                *(int2*)(vht + ((size_t)((bb * 16 + hh) * 64 + dd)) * 2048 + kk2) = u;
            }
    } else {
        unsigned short* OUT = proj == 0 ? qh : kh;
        const float osc = proj == 0 ? 0.125f : 1.0f;
        #pragma unroll
        for (int mi = 0; mi < 4; mi++)
            #pragma unroll
            for (int ni = 0; ni < 4; ni++) {
                int c = n0 + wc * 64 + ni * 16 + li;
                float bl = bias[c];
                int hh = c >> 6, dd = c & 63;
                int row0 = m0 + wr * 64 + mi * 16 + g * 4;
                #pragma unroll
                for (int j = 0; j < 4; j++) {
                    int row = row0 + j;
                    float val = acc[mi][ni][j] + bl;
                    OUT[(size_t)row * 1024 + c] = bf16s(val * osc);
                    if (proj == 0) {
                        int bb = row >> 11, lq = row & 2047;
                        __builtin_nontemporal_store(val,
                            qflat + (((size_t)(hh * 2 + bb)) * 2048 + lq) * 64 + dd);
                    }
                }
            }
    }
}

// ---------------- K2: fused attention ----------------
// pass 1: 2 K-tiles per barrier, 4 K buffers in lds_all[0..3].
// pass 2: counted-vmcnt pipeline, P stores via L2; lds_all[0..1]=K dbuf,
//         lds_all[2..3]=Vt dbuf. grid (16 qt, 32 hb), 512 thr = 8 waves.
__global__ __launch_bounds__(512, 4) void attn_kernel(
    const unsigned short* __restrict__ qh, const unsigned short* __restrict__ kh,
    const unsigned short* __restrict__ vht, float* __restrict__ attn_out,
    unsigned short* __restrict__ ctx)
{
    __shared__ unsigned short lds_all[4][8192];  // 64KB: pass1 K bufs / pass2 K+Vt dbufs
    __shared__ unsigned short lds_p[8192];       // P[128 q][64 k] swizzled (16KB)

    const int qt = blockIdx.x, hb = blockIdx.y;
    const int h = hb >> 1, b_ = hb & 1;
    const int q0 = qt * 128;
    const int t = threadIdx.x, l = t & 63, w = t >> 6;
    const int li = l & 15, g = l >> 4;

    const unsigned short* Qb = qh + (size_t)(b_ * 2048 + q0) * 1024 + h * 64;
    const unsigned short* Kb = kh + (size_t)(b_ * 2048) * 1024 + h * 64;
    const unsigned short* VTb = vht + (size_t)(b_ * 16 + h) * 131072;   // [64][2048]
    float* Ab = attn_out + ((size_t)hb * 2048 + q0) * 2048;

    // Q fragments (pre-scaled by 1/8 in qh)
    bf16x8 aq[2];
    #pragma unroll
    for (int kk = 0; kk < 2; kk++)
        aq[kk] = *(const bf16x8*)(Qb + (size_t)(w * 16 + li) * 1024 + kk * 32 + g * 8);

    const int sr8 = l >> 3;
    const int us8 = (l & 7) ^ sr8;

#define STAGE_KP(KT, BI) do { \
    _Pragma("unroll") \
    for (int c = 0; c < 2; c++) { \
        int r_ = w * 16 + c * 8 + sr8; \
        __builtin_amdgcn_global_load_lds(AS1(Kb + (size_t)((KT) * 128 + r_) * 1024 + us8 * 8), \
            AS3(&lds_all[BI][w * 1024 + c * 512]), 16, 0, 0); \
    } } while (0)

#define QKT_P(BI, S) do { \
    _Pragma("unroll") \
    for (int ni = 0; ni < 8; ni++) (S)[ni] = (f32x4){0.f, 0.f, 0.f, 0.f}; \
    __builtin_amdgcn_s_setprio(1); \
    _Pragma("unroll") \
    for (int kk = 0; kk < 2; kk++) { \
        int us = ((kk * 4 + g) ^ (li & 7)) * 8; \
        _Pragma("unroll") \
        for (int ni = 0; ni < 8; ni++) { \
            bf16x8 bk = *(bf16x8*)&lds_all[BI][(ni * 16 + li) * 64 + us]; \
            (S)[ni] = __builtin_amdgcn_mfma_f32_16x16x32_bf16(bk, aq[kk], (S)[ni], 0, 0, 0); \
        } \
    } \
    __builtin_amdgcn_s_setprio(0); \
    } while (0)

    // ---- pass 1: row sums of exp(S); 2 tiles per barrier, 4 K buffers ----
    float ssum = 0.f;
    {
        STAGE_KP(0, 0);
        STAGE_KP(1, 1);
        __syncthreads();
        for (int p = 0; p < 8; p++) {
            const int t0 = 2 * p;
            if (p < 7) {
                STAGE_KP(t0 + 2, (t0 + 2) & 3);
                STAGE_KP(t0 + 3, (t0 + 3) & 3);
            }
            f32x4 s1[8];
            QKT_P(t0 & 3, s1);
            float ps = 0.f;
            #pragma unroll
            for (int ni = 0; ni < 8; ni++)
                #pragma unroll
                for (int j = 0; j < 4; j++) ps += __expf(s1[ni][j]);
            ssum += ps;
            QKT_P((t0 + 1) & 3, s1);
            ps = 0.f;
            #pragma unroll
            for (int ni = 0; ni < 8; ni++)
                #pragma unroll
                for (int j = 0; j < 4; j++) ps += __expf(s1[ni][j]);
            ssum += ps;
            __syncthreads();
        }
    }
    ssum += __shfl_xor(ssum, 16, 64);
    ssum += __shfl_xor(ssum, 32, 64);
    const float rl = 1.f / ssum;

    // ---- pass 2: counted-vmcnt pipeline; P stores via L2 ----
    f32x4 cacc[4];
    #pragma unroll
    for (int ni = 0; ni < 4; ni++) cacc[ni] = (f32x4){0.f, 0.f, 0.f, 0.f};

    const int vd0 = w * 4 + g;
    const int vd1 = vd0 + 32;
    const int vsl0 = (li ^ (vd0 & 15)) * 8;
    const int vsl1 = (li ^ (vd1 & 15)) * 8;

    // prologue: K(0) -> lds_all[0], Vt(0) -> lds_all[2]
    STAGE_KP(0, 0);
    {
        int4 va0 = *(const int4*)(VTb + (size_t)vd0 * 2048 + li * 8);
        int4 vb0 = *(const int4*)(VTb + (size_t)vd1 * 2048 + li * 8);
        *(int4*)&lds_all[2][vd0 * 128 + vsl0] = va0;
        *(int4*)&lds_all[2][vd1 * 128 + vsl1] = vb0;
    }
    __syncthreads();   // drains prologue loads (no stores in flight yet)

    f32x4 s[8];     // holds normalized P after exp; flushed next iteration
    for (int kt = 0; kt < 16; kt++) {
        const int cur = kt & 1;
        // (1) issue next-tile loads FIRST (oldest in queue -> drained by vmcnt(8))
        int4 va, vb;
        if (kt < 15) {
            STAGE_KP(kt + 1, cur ^ 1);
            va = *(const int4*)(VTb + (size_t)vd0 * 2048 + (kt + 1) * 128 + li * 8);
            vb = *(const int4*)(VTb + (size_t)vd1 * 2048 + (kt + 1) * 128 + li * 8);
        }
        // (2) deferred attn stores of tile kt-1 (regular stores: L2 write-back)
        if (kt > 0) {
            #pragma unroll
            for (int ni = 0; ni < 8; ni++)
                *(f32x4*)(Ab + (size_t)(w * 16 + li) * 2048 + (kt - 1) * 128 + ni * 16 + 4 * g) = s[ni];
        }
        // (3) compute
        QKT_P(cur, s);
        #pragma unroll
        for (int half = 0; half < 2; half++) {
            #pragma unroll
            for (int ni4 = 0; ni4 < 4; ni4++) {
                int ni = half * 4 + ni4;
                float p0 = __expf(s[ni][0]) * rl;
                float p1 = __expf(s[ni][1]) * rl;
                float p2 = __expf(s[ni][2]) * rl;
                float p3 = __expf(s[ni][3]) * rl;
                s[ni] = (f32x4){p0, p1, p2, p3};
                int chunk = (2 * ni4 + (g >> 1)) ^ (li & 7);
                int base = (w * 16 + li) * 64 + chunk * 8 + 4 * (g & 1);
                int2 pw; pw.x = (int)pk2(p0, p1); pw.y = (int)pk2(p2, p3);
                *(int2*)&lds_p[base] = pw;
            }
            __builtin_amdgcn_s_setprio(1);
            #pragma unroll
            for (int ks = 0; ks < 2; ks++) {
                int us = ((ks * 4 + g) ^ (li & 7)) * 8;
                bf16x8 ap = *(bf16x8*)&lds_p[(w * 16 + li) * 64 + us];
                int vus = (((half * 2 + ks) * 4 + g) ^ li) * 8;
                #pragma unroll
                for (int ni = 0; ni < 4; ni++) {
                    bf16x8 bv2 = *(bf16x8*)&lds_all[2 + cur][(ni * 16 + li) * 128 + vus];
                    cacc[ni] = __builtin_amdgcn_mfma_f32_16x16x32_bf16(ap, bv2, cacc[ni], 0, 0, 0);
                }
            }
            __builtin_amdgcn_s_setprio(0);
        }
        // (4) counted wait: drain this tile's 4 loads (+ prior stores' L2 ack),
        //     keep this tile's 8 attn stores in flight across the barrier.
        if (kt == 0) {
            asm volatile("s_waitcnt vmcnt(0)" ::: "memory");
        } else {
            asm volatile("s_waitcnt vmcnt(8)" ::: "memory");
        }
        if (kt < 15) {
            *(int4*)&lds_all[2 + (cur ^ 1)][vd0 * 128 + vsl0] = va;
            *(int4*)&lds_all[2 + (cur ^ 1)][vd1 * 128 + vsl1] = vb;
        }
        asm volatile("s_waitcnt lgkmcnt(0)" ::: "memory");
        __builtin_amdgcn_s_barrier();
        __builtin_amdgcn_sched_barrier(0);
    }
    // flush last tile's attn stores
    #pragma unroll
    for (int ni = 0; ni < 8; ni++)
        *(f32x4*)(Ab + (size_t)(w * 16 + li) * 2048 + 15 * 128 + ni * 16 + 4 * g) = s[ni];
#undef STAGE_KP
#undef QKT_P

    #pragma unroll
    for (int ni = 0; ni < 4; ni++)
        #pragma unroll
        for (int j = 0; j < 4; j++) {
            int r = w * 16 + g * 4 + j;
            int d = ni * 16 + li;
            ctx[(size_t)(b_ * 2048 + q0 + r) * 1024 + h * 64 + d] = bf16s(cacc[ni][j]);
        }
}

// ---------------- K3: FC GEMM + bias + residual ----------------
__global__ __launch_bounds__(256, 3) void fc_kernel(
    const unsigned short* __restrict__ ctx, const unsigned short* __restrict__ wfcb,
    const float* __restrict__ bfc, const float* __restrict__ resid,
    float* __restrict__ xout)
{
    __shared__ unsigned short lds_a[128 * 64];
    __shared__ unsigned short lds_b[128 * 64];

    const int n0 = blockIdx.x * 128;
    const int m0 = blockIdx.y * 128;
    const int t = threadIdx.x, l = t & 63, w = t >> 6;
    const int wr = w >> 1, wc = w & 1;
    const int li = l & 15, g = l >> 4;
    const int sr = l >> 3;
    const int us_st = (l & 7) ^ sr;

    f32x4 acc[4][4];
    #pragma unroll
    for (int i = 0; i < 4; i++)
        #pragma unroll
        for (int j = 0; j < 4; j++) acc[i][j] = (f32x4){0.f, 0.f, 0.f, 0.f};

    for (int k0 = 0; k0 < 1024; k0 += 64) {
        __syncthreads();
        #pragma unroll
        for (int i = 0; i < 4; i++) {
            int r = i * 32 + w * 8 + sr;
            __builtin_amdgcn_global_load_lds(AS1(ctx + (size_t)(m0 + r) * 1024 + k0 + us_st * 8),
                                             AS3(lds_a + (i * 256 + w * 64) * 8), 16, 0, 0);
            __builtin_amdgcn_global_load_lds(AS1(wfcb + (size_t)(n0 + r) * 1024 + k0 + us_st * 8),
                                             AS3(lds_b + (i * 256 + w * 64) * 8), 16, 0, 0);
        }
        __syncthreads();
        #pragma unroll
        for (int kk = 0; kk < 2; kk++) {
            bf16x8 af[4], bfr[4];
            int us = (kk * 4 + g) ^ (li & 7);
            #pragma unroll
            for (int mi = 0; mi < 4; mi++)
                af[mi] = *(bf16x8*)&lds_a[(wr * 64 + mi * 16 + li) * 64 + us * 8];
            #pragma unroll
            for (int ni = 0; ni < 4; ni++)
                bfr[ni] = *(bf16x8*)&lds_b[(wc * 64 + ni * 16 + li) * 64 + us * 8];
            #pragma unroll
            for (int mi = 0; mi < 4; mi++)
                #pragma unroll
                for (int ni = 0; ni < 4; ni++)
                    acc[mi][ni] = __builtin_amdgcn_mfma_f32_16x16x32_bf16(af[mi], bfr[ni], acc[mi][ni], 0, 0, 0);
        }
    }

    #pragma unroll
    for (int mi = 0; mi < 4; mi++)
        #pragma unroll
        for (int ni = 0; ni < 4; ni++) {
            int col = n0 + wc * 64 + ni * 16 + li;
            float bl = bfc[col];
            #pragma unroll
            for (int j = 0; j < 4; j++) {
                int row = m0 + wr * 64 + mi * 16 + g * 4 + j;
                float val = acc[mi][ni][j] + bl + resid[(size_t)row * 1024 + col];
                xout[(size_t)row * 1024 + col] = val;
            }
        }
}

// ---------------- K4: layernorm (in place) ----------------
__global__ __launch_bounds__(256) void ln_kernel(
    float* __restrict__ x, const float* __restrict__ gamma,
    const float* __restrict__ beta)
{
    __shared__ float red[2][4];
    const int row = blockIdx.x;
    const int t = threadIdx.x;
    float4 v = *(const float4*)(x + (size_t)row * 1024 + t * 4);
    float s = v.x + v.y + v.z + v.w;
    float ss = v.x * v.x + v.y * v.y + v.z * v.z + v.w * v.w;
    #pragma unroll
    for (int msk = 1; msk < 64; msk <<= 1) {
        s += __shfl_xor(s, msk, 64);
        ss += __shfl_xor(ss, msk, 64);
    }
    int w = t >> 6, l = t & 63;
    if (l == 0) { red[0][w] = s; red[1][w] = ss; }
    __syncthreads();
    s = red[0][0] + red[0][1] + red[0][2] + red[0][3];
    ss = red[1][0] + red[1][1] + red[1][2] + red[1][3];
    float mean = s * (1.f / 1024.f);
    float var = ss * (1.f / 1024.f) - mean * mean;
    float rstd = rsqrtf(var + 1e-5f);
    float4 g4 = *(const float4*)(gamma + t * 4);
    float4 b4 = *(const float4*)(beta + t * 4);
    float4 o;
    o.x = (v.x - mean) * rstd * g4.x + b4.x;
    o.y = (v.y - mean) * rstd * g4.y + b4.y;
    o.z = (v.z - mean) * rstd * g4.z + b4.z;
    o.w = (v.w - mean) * rstd * g4.w + b4.w;
    *(float4*)(x + (size_t)row * 1024 + t * 4) = o;
}

extern "C" void kernel_launch(void* const* d_in, const int* in_sizes, int n_in,
                              void* d_out, int out_size, void* d_ws, size_t ws_size,
                              hipStream_t stream)
{
    const float* q     = (const float*)d_in[0];
    const float* k     = (const float*)d_in[1];
    const float* v     = (const float*)d_in[2];
    const float* Wq    = (const float*)d_in[3];
    const float* bq    = (const float*)d_in[4];
    const float* Wk    = (const float*)d_in[5];
    const float* bk    = (const float*)d_in[6];
    const float* Wv    = (const float*)d_in[7];
    const float* bv    = (const float*)d_in[8];
    const float* Wfc   = (const float*)d_in[9];
    const float* bfc   = (const float*)d_in[10];
    const float* gamma = (const float*)d_in[11];
    const float* beta  = (const float*)d_in[12];

    float* y     = (float*)d_out;
    float* attn  = (float*)d_out + 4194304;                 // 4096*1024
    float* qflat = (float*)d_out + 4194304 + 134217728;     // + 32*2048*2048

    // xb (24MB bf16) borrows the attn region: dead before K2 overwrites it.
    unsigned short* xb = (unsigned short*)attn;

    // ws layout (bytes): qh@0, kh@8M, vht@16M, ctx@24M, wb@32M  (total 40MB)
    char* ws = (char*)d_ws;
    unsigned short* qh  = (unsigned short*)(ws);
    unsigned short* kh  = (unsigned short*)(ws + 8388608ull);
    unsigned short* vht = (unsigned short*)(ws + 16777216ull);
    unsigned short* ctx = (unsigned short*)(ws + 25165824ull);
    unsigned short* wb  = (unsigned short*)(ws + 33554432ull);

    convert_kernel<<<8192, 256, 0, stream>>>(q, k, v, Wq, Wk, Wv, Wfc, xb, wb);
    qkv_proj_kernel<<<dim3(24, 32), 256, 0, stream>>>(xb, wb, bq, bk, bv, qh, kh, vht, qflat);
    attn_kernel<<<dim3(16, 32), 512, 0, stream>>>(qh, kh, vht, attn, ctx);
    fc_kernel<<<dim3(8, 32), 256, 0, stream>>>(ctx, wb + 3145728, bfc, q, y);
    ln_kernel<<<4096, 256, 0, stream>>>(y, gamma, beta);
}

// Round 15
// 264.452 us; speedup vs baseline: 1.1051x; 1.1051x over previous
//
#include <hip/hip_runtime.h>

typedef __attribute__((ext_vector_type(8))) __bf16 bf16x8;
typedef __attribute__((ext_vector_type(4))) float f32x4;

__device__ __forceinline__ unsigned short bf16s(float f) {
    __bf16 b = (__bf16)f;
    unsigned short u;
    __builtin_memcpy(&u, &b, 2);
    return u;
}
__device__ __forceinline__ unsigned pk2(float a, float b) {
    __bf16 lo = (__bf16)a, hi = (__bf16)b;
    unsigned short ul, uh;
    __builtin_memcpy(&ul, &lo, 2);
    __builtin_memcpy(&uh, &hi, 2);
    return (unsigned)ul | ((unsigned)uh << 16);
}
#define AS1(p) ((const __attribute__((address_space(1))) void*)(p))
#define AS3(p) ((__attribute__((address_space(3))) void*)(p))

// ---------------- K0: one-shot fp32 -> bf16 conversion of X (q,k,v) and W ----------------
__global__ __launch_bounds__(256) void convert_kernel(
    const float* __restrict__ q, const float* __restrict__ k, const float* __restrict__ v,
    const float* __restrict__ Wq, const float* __restrict__ Wk,
    const float* __restrict__ Wv, const float* __restrict__ Wfc,
    unsigned short* __restrict__ xb, unsigned short* __restrict__ wb)
{
    size_t i = ((size_t)blockIdx.x * 256 + threadIdx.x) * 8;
    const float* src;
    unsigned short* dst;
    size_t off;
    if (i < 12582912ull) {
        int a = (int)(i >> 22);
        src = a == 0 ? q : a == 1 ? k : v;
        off = i & 4194303ull;
        dst = xb + i;
    } else {
        size_t wi = i - 12582912ull;
        int a = (int)(wi >> 20);
        src = a == 0 ? Wq : a == 1 ? Wk : a == 2 ? Wv : Wfc;
        off = wi & 1048575ull;
        dst = wb + wi;
    }
    float4 v0 = *(const float4*)(src + off);
    float4 v1 = *(const float4*)(src + off + 4);
    int4 o;
    o.x = (int)pk2(v0.x, v0.y);
    o.y = (int)pk2(v0.z, v0.w);
    o.z = (int)pk2(v1.x, v1.y);
    o.w = (int)pk2(v1.z, v1.w);
    *(int4*)dst = o;
}

// ---------------- K1: QKV projection GEMM (bf16 in, + q_flat + vh transposed) ----------------
// qh is written PRE-SCALED by 1/8 (exact in bf16); qflat unscaled.
__global__ __launch_bounds__(256, 3) void qkv_proj_kernel(
    const unsigned short* __restrict__ xb, const unsigned short* __restrict__ wb,
    const float* __restrict__ bq, const float* __restrict__ bk, const float* __restrict__ bv,
    unsigned short* __restrict__ qh, unsigned short* __restrict__ kh,
    unsigned short* __restrict__ vht, float* __restrict__ qflat)
{
    __shared__ unsigned short lds_a[128 * 64];
    __shared__ unsigned short lds_b[128 * 64];

    const int nb = blockIdx.x;
    const int mb = blockIdx.y;
    const int proj = nb >> 3;
    const int n0 = (nb & 7) * 128;
    const int m0 = mb * 128;

    const unsigned short* A = xb + (size_t)proj * 4194304;
    const unsigned short* B = wb + (size_t)proj * 1048576;
    const float* bias = proj == 0 ? bq : proj == 1 ? bk : bv;

    const int t = threadIdx.x, l = t & 63, w = t >> 6;
    const int wr = w >> 1, wc = w & 1;
    const int li = l & 15, g = l >> 4;
    const int sr = l >> 3;
    const int us_st = (l & 7) ^ sr;

    f32x4 acc[4][4];
    #pragma unroll
    for (int i = 0; i < 4; i++)
        #pragma unroll
        for (int j = 0; j < 4; j++) acc[i][j] = (f32x4){0.f, 0.f, 0.f, 0.f};

    for (int k0 = 0; k0 < 1024; k0 += 64) {
        __syncthreads();
        #pragma unroll
        for (int i = 0; i < 4; i++) {
            int r = i * 32 + w * 8 + sr;
            __builtin_amdgcn_global_load_lds(AS1(A + (size_t)(m0 + r) * 1024 + k0 + us_st * 8),
                                             AS3(lds_a + (i * 256 + w * 64) * 8), 16, 0, 0);
            __builtin_amdgcn_global_load_lds(AS1(B + (size_t)(n0 + r) * 1024 + k0 + us_st * 8),
                                             AS3(lds_b + (i * 256 + w * 64) * 8), 16, 0, 0);
        }
        __syncthreads();
        #pragma unroll
        for (int kk = 0; kk < 2; kk++) {
            bf16x8 af[4], bfr[4];
            int us = (kk * 4 + g) ^ (li & 7);
            #pragma unroll
            for (int mi = 0; mi < 4; mi++)
                af[mi] = *(bf16x8*)&lds_a[(wr * 64 + mi * 16 + li) * 64 + us * 8];
            #pragma unroll
            for (int ni = 0; ni < 4; ni++)
                bfr[ni] = *(bf16x8*)&lds_b[(wc * 64 + ni * 16 + li) * 64 + us * 8];
            #pragma unroll
            for (int mi = 0; mi < 4; mi++)
                #pragma unroll
                for (int ni = 0; ni < 4; ni++)
                    acc[mi][ni] = __builtin_amdgcn_mfma_f32_16x16x32_bf16(af[mi], bfr[ni], acc[mi][ni], 0, 0, 0);
        }
    }

    if (proj == 2) {
        #pragma unroll
        for (int mi = 0; mi < 4; mi++)
            #pragma unroll
            for (int ni = 0; ni < 4; ni++) {
                int c = n0 + wc * 64 + ni * 16 + li;
                float bl = bias[c];
                int hh = c >> 6, dd = c & 63;
                int row0 = m0 + wr * 64 + mi * 16 + g * 4;
                int bb = row0 >> 11, kk2 = row0 & 2047;
                unsigned lo = pk2(acc[mi][ni][0] + bl, acc[mi][ni][1] + bl);
                unsigned hi = pk2(acc[mi][ni][2] + bl, acc[mi][ni][3] + bl);
                int2 u; u.x = (int)lo; u.y = (int)hi;
                *(int2*)(vht + ((size_t)((bb * 16 + hh) * 64 + dd)) * 2048 + kk2) = u;
            }
    } else {
        unsigned short* OUT = proj == 0 ? qh : kh;
        const float osc = proj == 0 ? 0.125f : 1.0f;
        #pragma unroll
        for (int mi = 0; mi < 4; mi++)
            #pragma unroll
            for (int ni = 0; ni < 4; ni++) {
                int c = n0 + wc * 64 + ni * 16 + li;
                float bl = bias[c];
                int hh = c >> 6, dd = c & 63;
                int row0 = m0 + wr * 64 + mi * 16 + g * 4;
                #pragma unroll
                for (int j = 0; j < 4; j++) {
                    int row = row0 + j;
                    float val = acc[mi][ni][j] + bl;
                    OUT[(size_t)row * 1024 + c] = bf16s(val * osc);
                    if (proj == 0) {
                        int bb = row >> 11, lq = row & 2047;
                        __builtin_nontemporal_store(val,
                            qflat + (((size_t)(hh * 2 + bb)) * 2048 + lq) * 64 + dd);
                    }
                }
            }
    }
}

// ---------------- K2: fused attention (R11 best: pass1 dbuf, pass2 counted-vmcnt, L2 stores) ----------------
// grid (16 qtiles, 32 hb), 512 thr = 8 waves; wave w owns q-rows w*16..w*16+15.
__global__ __launch_bounds__(512, 4) void attn_kernel(
    const unsigned short* __restrict__ qh, const unsigned short* __restrict__ kh,
    const unsigned short* __restrict__ vht, float* __restrict__ attn_out,
    unsigned short* __restrict__ ctx)
{
    __shared__ unsigned short lds_k[2][8192];   // K[128][64] swizzled, dbuf   (32KB)
    __shared__ unsigned short lds_vt[2][8192];  // Vt[64][128] swizzled, dbuf  (32KB)
    __shared__ unsigned short lds_p[8192];      // P[128 q][64 k] swizzled     (16KB)

    const int qt = blockIdx.x, hb = blockIdx.y;
    const int h = hb >> 1, b_ = hb & 1;
    const int q0 = qt * 128;
    const int t = threadIdx.x, l = t & 63, w = t >> 6;
    const int li = l & 15, g = l >> 4;

    const unsigned short* Qb = qh + (size_t)(b_ * 2048 + q0) * 1024 + h * 64;
    const unsigned short* Kb = kh + (size_t)(b_ * 2048) * 1024 + h * 64;
    const unsigned short* VTb = vht + (size_t)(b_ * 16 + h) * 131072;   // [64][2048]
    float* Ab = attn_out + ((size_t)hb * 2048 + q0) * 2048;

    // Q fragments (pre-scaled by 1/8 in qh)
    bf16x8 aq[2];
    #pragma unroll
    for (int kk = 0; kk < 2; kk++)
        aq[kk] = *(const bf16x8*)(Qb + (size_t)(w * 16 + li) * 1024 + kk * 32 + g * 8);

    const int sr8 = l >> 3;
    const int us8 = (l & 7) ^ sr8;

#define STAGE_K(KT, BUF) do { \
    _Pragma("unroll") \
    for (int c = 0; c < 2; c++) { \
        int r_ = w * 16 + c * 8 + sr8; \
        __builtin_amdgcn_global_load_lds(AS1(Kb + (size_t)((KT) * 128 + r_) * 1024 + us8 * 8), \
            AS3(lds_k[BUF] + w * 1024 + c * 512), 16, 0, 0); \
    } } while (0)

#define QKT(BUF, S) do { \
    _Pragma("unroll") \
    for (int ni = 0; ni < 8; ni++) (S)[ni] = (f32x4){0.f, 0.f, 0.f, 0.f}; \
    __builtin_amdgcn_s_setprio(1); \
    _Pragma("unroll") \
    for (int kk = 0; kk < 2; kk++) { \
        int us = ((kk * 4 + g) ^ (li & 7)) * 8; \
        _Pragma("unroll") \
        for (int ni = 0; ni < 8; ni++) { \
            bf16x8 bk = *(bf16x8*)&lds_k[BUF][(ni * 16 + li) * 64 + us]; \
            (S)[ni] = __builtin_amdgcn_mfma_f32_16x16x32_bf16(bk, aq[kk], (S)[ni], 0, 0, 0); \
        } \
    } \
    __builtin_amdgcn_s_setprio(0); \
    } while (0)

    // ---- pass 1: row sums of exp(S) (LDS-staged K dbuf, 1 barrier/tile) ----
    float ssum = 0.f;
    STAGE_K(0, 0);
    __syncthreads();
    for (int kt = 0; kt < 16; kt++) {
        const int cur = kt & 1;
        if (kt < 15) STAGE_K(kt + 1, cur ^ 1);
        f32x4 s1[8];
        QKT(cur, s1);
        float ps = 0.f;
        #pragma unroll
        for (int ni = 0; ni < 8; ni++)
            #pragma unroll
            for (int j = 0; j < 4; j++) ps += __expf(s1[ni][j]);
        ssum += ps;
        __syncthreads();
    }
    ssum += __shfl_xor(ssum, 16, 64);
    ssum += __shfl_xor(ssum, 32, 64);
    const float rl = 1.f / ssum;

    // ---- pass 2: counted-vmcnt pipeline; P stores go through L2 ----
    f32x4 cacc[4];
    #pragma unroll
    for (int ni = 0; ni < 4; ni++) cacc[ni] = (f32x4){0.f, 0.f, 0.f, 0.f};

    const int vd0 = w * 4 + g;
    const int vd1 = vd0 + 32;
    const int vsl0 = (li ^ (vd0 & 15)) * 8;
    const int vsl1 = (li ^ (vd1 & 15)) * 8;

    // prologue: K(0), Vt(0)
    STAGE_K(0, 0);
    {
        int4 va0 = *(const int4*)(VTb + (size_t)vd0 * 2048 + li * 8);
        int4 vb0 = *(const int4*)(VTb + (size_t)vd1 * 2048 + li * 8);
        *(int4*)&lds_vt[0][vd0 * 128 + vsl0] = va0;
        *(int4*)&lds_vt[0][vd1 * 128 + vsl1] = vb0;
    }
    __syncthreads();   // drains prologue loads (no stores in flight yet)

    f32x4 s[8];     // holds normalized P after exp; flushed next iteration
    for (int kt = 0; kt < 16; kt++) {
        const int cur = kt & 1;
        // (1) issue next-tile loads FIRST (oldest in queue -> drained by vmcnt(8))
        int4 va, vb;
        if (kt < 15) {
            STAGE_K(kt + 1, cur ^ 1);
            va = *(const int4*)(VTb + (size_t)vd0 * 2048 + (kt + 1) * 128 + li * 8);
            vb = *(const int4*)(VTb + (size_t)vd1 * 2048 + (kt + 1) * 128 + li * 8);
        }
        // (2) deferred attn stores of tile kt-1 (regular stores: L2 write-back)
        if (kt > 0) {
            #pragma unroll
            for (int ni = 0; ni < 8; ni++)
                *(f32x4*)(Ab + (size_t)(w * 16 + li) * 2048 + (kt - 1) * 128 + ni * 16 + 4 * g) = s[ni];
        }
        // (3) compute
        QKT(cur, s);
        #pragma unroll
        for (int half = 0; half < 2; half++) {
            #pragma unroll
            for (int ni4 = 0; ni4 < 4; ni4++) {
                int ni = half * 4 + ni4;
                float p0 = __expf(s[ni][0]) * rl;
                float p1 = __expf(s[ni][1]) * rl;
                float p2 = __expf(s[ni][2]) * rl;
                float p3 = __expf(s[ni][3]) * rl;
                s[ni] = (f32x4){p0, p1, p2, p3};
                int chunk = (2 * ni4 + (g >> 1)) ^ (li & 7);
                int base = (w * 16 + li) * 64 + chunk * 8 + 4 * (g & 1);
                int2 pw; pw.x = (int)pk2(p0, p1); pw.y = (int)pk2(p2, p3);
                *(int2*)&lds_p[base] = pw;
            }
            __builtin_amdgcn_s_setprio(1);
            #pragma unroll
            for (int ks = 0; ks < 2; ks++) {
                int us = ((ks * 4 + g) ^ (li & 7)) * 8;
                bf16x8 ap = *(bf16x8*)&lds_p[(w * 16 + li) * 64 + us];
                int vus = (((half * 2 + ks) * 4 + g) ^ li) * 8;
                #pragma unroll
                for (int ni = 0; ni < 4; ni++) {
                    bf16x8 bv2 = *(bf16x8*)&lds_vt[cur][(ni * 16 + li) * 128 + vus];
                    cacc[ni] = __builtin_amdgcn_mfma_f32_16x16x32_bf16(ap, bv2, cacc[ni], 0, 0, 0);
                }
            }
            __builtin_amdgcn_s_setprio(0);
        }
        // (4) counted wait: drain this tile's 4 loads (+ prior stores' L2 ack),
        //     keep this tile's 8 attn stores in flight across the barrier.
        if (kt == 0) {
            asm volatile("s_waitcnt vmcnt(0)" ::: "memory");
        } else {
            asm volatile("s_waitcnt vmcnt(8)" ::: "memory");
        }
        if (kt < 15) {
            *(int4*)&lds_vt[cur ^ 1][vd0 * 128 + vsl0] = va;
            *(int4*)&lds_vt[cur ^ 1][vd1 * 128 + vsl1] = vb;
        }
        asm volatile("s_waitcnt lgkmcnt(0)" ::: "memory");
        __builtin_amdgcn_s_barrier();
        __builtin_amdgcn_sched_barrier(0);
    }
    // flush last tile's attn stores
    #pragma unroll
    for (int ni = 0; ni < 8; ni++)
        *(f32x4*)(Ab + (size_t)(w * 16 + li) * 2048 + 15 * 128 + ni * 16 + 4 * g) = s[ni];
#undef STAGE_K
#undef QKT

    #pragma unroll
    for (int ni = 0; ni < 4; ni++)
        #pragma unroll
        for (int j = 0; j < 4; j++) {
            int r = w * 16 + g * 4 + j;
            int d = ni * 16 + li;
            ctx[(size_t)(b_ * 2048 + q0 + r) * 1024 + h * 64 + d] = bf16s(cacc[ni][j]);
        }
}

// ---------------- K3: FC GEMM + bias + residual (128x64 tiles, 2 blocks/CU) ----------------
__global__ __launch_bounds__(256) void fc_kernel(
    const unsigned short* __restrict__ ctx, const unsigned short* __restrict__ wfcb,
    const float* __restrict__ bfc, const float* __restrict__ resid,
    float* __restrict__ xout)
{
    __shared__ unsigned short lds_a[128 * 64];   // 16KB
    __shared__ unsigned short lds_b[64 * 64];    // 8KB

    const int n0 = blockIdx.x * 64;
    const int m0 = blockIdx.y * 128;
    const int t = threadIdx.x, l = t & 63, w = t >> 6;
    const int wr = w >> 1, wc = w & 1;
    const int li = l & 15, g = l >> 4;
    const int sr = l >> 3;
    const int us_st = (l & 7) ^ sr;

    f32x4 acc[4][2];
    #pragma unroll
    for (int i = 0; i < 4; i++)
        #pragma unroll
        for (int j = 0; j < 2; j++) acc[i][j] = (f32x4){0.f, 0.f, 0.f, 0.f};

    for (int k0 = 0; k0 < 1024; k0 += 64) {
        __syncthreads();
        #pragma unroll
        for (int i = 0; i < 4; i++) {
            int r = i * 32 + w * 8 + sr;
            __builtin_amdgcn_global_load_lds(AS1(ctx + (size_t)(m0 + r) * 1024 + k0 + us_st * 8),
                                             AS3(lds_a + (i * 256 + w * 64) * 8), 16, 0, 0);
        }
        #pragma unroll
        for (int i = 0; i < 2; i++) {
            int r = i * 32 + w * 8 + sr;
            __builtin_amdgcn_global_load_lds(AS1(wfcb + (size_t)(n0 + r) * 1024 + k0 + us_st * 8),
                                             AS3(lds_b + (i * 256 + w * 64) * 8), 16, 0, 0);
        }
        __syncthreads();
        #pragma unroll
        for (int kk = 0; kk < 2; kk++) {
            bf16x8 af[4], bfr[2];
            int us = (kk * 4 + g) ^ (li & 7);
            #pragma unroll
            for (int mi = 0; mi < 4; mi++)
                af[mi] = *(bf16x8*)&lds_a[(wr * 64 + mi * 16 + li) * 64 + us * 8];
            #pragma unroll
            for (int ni = 0; ni < 2; ni++)
                bfr[ni] = *(bf16x8*)&lds_b[(wc * 32 + ni * 16 + li) * 64 + us * 8];
            #pragma unroll
            for (int mi = 0; mi < 4; mi++)
                #pragma unroll
                for (int ni = 0; ni < 2; ni++)
                    acc[mi][ni] = __builtin_amdgcn_mfma_f32_16x16x32_bf16(af[mi], bfr[ni], acc[mi][ni], 0, 0, 0);
        }
    }

    #pragma unroll
    for (int mi = 0; mi < 4; mi++)
        #pragma unroll
        for (int ni = 0; ni < 2; ni++) {
            int col = n0 + wc * 32 + ni * 16 + li;
            float bl = bfc[col];
            #pragma unroll
            for (int j = 0; j < 4; j++) {
                int row = m0 + wr * 64 + mi * 16 + g * 4 + j;
                float val = acc[mi][ni][j] + bl + resid[(size_t)row * 1024 + col];
                xout[(size_t)row * 1024 + col] = val;
            }
        }
}

// ---------------- K4: layernorm (in place) ----------------
__global__ __launch_bounds__(256) void ln_kernel(
    float* __restrict__ x, const float* __restrict__ gamma,
    const float* __restrict__ beta)
{
    __shared__ float red[2][4];
    const int row = blockIdx.x;
    const int t = threadIdx.x;
    float4 v = *(const float4*)(x + (size_t)row * 1024 + t * 4);
    float s = v.x + v.y + v.z + v.w;
    float ss = v.x * v.x + v.y * v.y + v.z * v.z + v.w * v.w;
    #pragma unroll
    for (int msk = 1; msk < 64; msk <<= 1) {
        s += __shfl_xor(s, msk, 64);
        ss += __shfl_xor(ss, msk, 64);
    }
    int w = t >> 6, l = t & 63;
    if (l == 0) { red[0][w] = s; red[1][w] = ss; }
    __syncthreads();
    s = red[0][0] + red[0][1] + red[0][2] + red[0][3];
    ss = red[1][0] + red[1][1] + red[1][2] + red[1][3];
    float mean = s * (1.f / 1024.f);
    float var = ss * (1.f / 1024.f) - mean * mean;
    float rstd = rsqrtf(var + 1e-5f);
    float4 g4 = *(const float4*)(gamma + t * 4);
    float4 b4 = *(const float4*)(beta + t * 4);
    float4 o;
    o.x = (v.x - mean) * rstd * g4.x + b4.x;
    o.y = (v.y - mean) * rstd * g4.y + b4.y;
    o.z = (v.z - mean) * rstd * g4.z + b4.z;
    o.w = (v.w - mean) * rstd * g4.w + b4.w;
    *(float4*)(x + (size_t)row * 1024 + t * 4) = o;
}

extern "C" void kernel_launch(void* const* d_in, const int* in_sizes, int n_in,
                              void* d_out, int out_size, void* d_ws, size_t ws_size,
                              hipStream_t stream)
{
    const float* q     = (const float*)d_in[0];
    const float* k     = (const float*)d_in[1];
    const float* v     = (const float*)d_in[2];
    const float* Wq    = (const float*)d_in[3];
    const float* bq    = (const float*)d_in[4];
    const float* Wk    = (const float*)d_in[5];
    const float* bk    = (const float*)d_in[6];
    const float* Wv    = (const float*)d_in[7];
    const float* bv    = (const float*)d_in[8];
    const float* Wfc   = (const float*)d_in[9];
    const float* bfc   = (const float*)d_in[10];
    const float* gamma = (const float*)d_in[11];
    const float* beta  = (const float*)d_in[12];

    float* y     = (float*)d_out;
    float* attn  = (float*)d_out + 4194304;                 // 4096*1024
    float* qflat = (float*)d_out + 4194304 + 134217728;     // + 32*2048*2048

    // xb (24MB bf16) borrows the attn region: dead before K2 overwrites it.
    unsigned short* xb = (unsigned short*)attn;

    // ws layout (bytes): qh@0, kh@8M, vht@16M, ctx@24M, wb@32M  (total 40MB)
    char* ws = (char*)d_ws;
    unsigned short* qh  = (unsigned short*)(ws);
    unsigned short* kh  = (unsigned short*)(ws + 8388608ull);
    unsigned short* vht = (unsigned short*)(ws + 16777216ull);
    unsigned short* ctx = (unsigned short*)(ws + 25165824ull);
    unsigned short* wb  = (unsigned short*)(ws + 33554432ull);

    convert_kernel<<<8192, 256, 0, stream>>>(q, k, v, Wq, Wk, Wv, Wfc, xb, wb);
    qkv_proj_kernel<<<dim3(24, 32), 256, 0, stream>>>(xb, wb, bq, bk, bv, qh, kh, vht, qflat);
    attn_kernel<<<dim3(16, 32), 512, 0, stream>>>(qh, kh, vht, attn, ctx);
    fc_kernel<<<dim3(16, 32), 256, 0, stream>>>(ctx, wb + 3145728, bfc, q, y);
    ln_kernel<<<4096, 256, 0, stream>>>(y, gamma, beta);
}